// Round 12
// baseline (552.718 us; speedup 1.0000x reference)
//
#include <hip/hip_runtime.h>
#include <cfloat>

// Problem constants
#define N_ROWS 32768
#define N_CLS  2048
#define DIM    512

typedef __attribute__((ext_vector_type(8))) short short8;
typedef __attribute__((ext_vector_type(4))) short short4v;
typedef __attribute__((ext_vector_type(4))) float f32x4;
typedef __attribute__((ext_vector_type(16))) float f32x16;

__device__ __forceinline__ unsigned f2bf_bits(float x) {
    union { float f; unsigned u; } a; a.f = x;
    return (a.u + 0x7fffu + ((a.u >> 16) & 1u)) >> 16;   // RNE
}
__device__ __forceinline__ float bf_to_f(unsigned bits) {
    union { unsigned u; float f; } a; a.u = bits << 16;
    return a.f;
}
__device__ __forceinline__ void split_bf(float x, short &h, short &l) {
    unsigned hb = f2bf_bits(x);
    h = (short)hb;
    float r = x - bf_to_f(hb);          // exact residual
    l = (short)f2bf_bits(r);
}

// ---------------- fused prep: split X, split muK, m2 — one launch (R9, kept) ----------
#define PREP_XB   16384
#define PREP_MB   1024
#define PREP_M2B  2048
__global__ __launch_bounds__(256) void prep_kernel(const float* __restrict__ X,
                                                   const float* __restrict__ muK,
                                                   short* __restrict__ Xh,
                                                   short* __restrict__ Xl,
                                                   short* __restrict__ Mh,
                                                   short* __restrict__ Ml,
                                                   float* __restrict__ m2) {
    const int b = blockIdx.x;
    if (b < PREP_XB + PREP_MB) {
        const bool isX = (b < PREP_XB);
        const float* src = isX ? X : muK;
        short* hi = isX ? Xh : Mh;
        short* lo = isX ? Xl : Ml;
        const int idx = (isX ? b : b - PREP_XB) * 256 + threadIdx.x;
        float4 v = ((const float4*)src)[idx];
        short h0, h1, h2, h3, l0, l1, l2, l3;
        split_bf(v.x, h0, l0); split_bf(v.y, h1, l1);
        split_bf(v.z, h2, l2); split_bf(v.w, h3, l3);
        ((short4v*)hi)[idx] = (short4v){h0, h1, h2, h3};
        ((short4v*)lo)[idx] = (short4v){l0, l1, l2, l3};
    } else {
        const int j = b - (PREP_XB + PREP_MB);
        const int t = threadIdx.x;
        const float* r = muK + (size_t)j * DIM;
        float a = r[t], c = r[t + 256];
        float s = a * a + c * c;
        for (int off = 32; off; off >>= 1) s += __shfl_xor(s, off);
        __shared__ float sw[4];
        if ((t & 63) == 0) sw[t >> 6] = s;
        __syncthreads();
        if (t == 0) m2[j] = sw[0] + sw[1] + sw[2] + sw[3];
    }
}

// ---------------- m2 standalone (fallback path only) ----------------
__global__ __launch_bounds__(256) void m2_kernel(const float* __restrict__ muK,
                                                 float* __restrict__ m2) {
    const int j = blockIdx.x;
    const int t = threadIdx.x;
    const float* r = muK + (size_t)j * DIM;
    float a = r[t], b = r[t + 256];
    float s = a * a + b * b;
    for (int off = 32; off; off >>= 1) s += __shfl_xor(s, off);
    __shared__ float sw[4];
    if ((t & 63) == 0) sw[t >> 6] = s;
    __syncthreads();
    if (t == 0) m2[j] = sw[0] + sw[1] + sw[2] + sw[3];
}

#define GLDS16(g, l) __builtin_amdgcn_global_load_lds( \
    (const __attribute__((address_space(1))) unsigned int*)(g), \
    (__attribute__((address_space(3))) unsigned int*)(l), 16, 0, 0)

// ---------------- fused bf16x3 GEMM: 256x256, 8 waves, R5 phases, 32x32x16 MFMA ----
// S[i,j] = 2 * (Xh.Mh + Xh.Ml + Xl.Mh)[i,j] - m2[j]
// R12: R11's 32x32x16 shape (absmax-verified) + k-half-contiguous LDS layout
// to kill R11's 12.58M bank conflicts (exactly 4/ds_read_b128 measured).
// Root cause: R11's fixed-h read touched 32 rows x 2-of-4 chunks = 1024B
// scattered over 2048B (half of each 128B line). Conflict-free R5 reads were
// DENSE 1024B. New layout per 32-row block (2048B): [h][row&31][hi] ->
// byte = block*2048 + h*1024 + (row&31)*32 + hi*16. A fixed-h read spans one
// dense 1024B slab; banks 8*(l32&3)+4*hi, 8 lanes/bank-group @128B stride —
// structurally identical to the R5 reader (0 conflicts).
// Permutation realized ENTIRELY on the staging source address (rule 21; LDS
// dest stays lane-linear as global_load_lds requires): chunk slot q holds
// global (row, g): row=(q>>7)*32+((q>>1)&31), g=2*((q>>6)&1)+(q&1).
// MFMA operand mapping unchanged: lane (l32,hi) gets chunk g=2h+hi of its row.
// MFMA order & epilogue byte-identical to R11 -> absmax unchanged (0.00390625).
__global__ __launch_bounds__(512, 2) void gemm_kernel(const short* __restrict__ Xh,
                                                      const short* __restrict__ Xl,
                                                      const short* __restrict__ Mh,
                                                      const short* __restrict__ Ml,
                                                      const float* __restrict__ m2,
                                                      float* __restrict__ S) {
    __shared__ __align__(16) short Ash[2][256 * 32];
    __shared__ __align__(16) short Asl[2][256 * 32];
    __shared__ __align__(16) short Bsh[2][256 * 32];
    __shared__ __align__(16) short Bsl[2][256 * 32];

    const int tid = threadIdx.x;

    // XCD-chunked bijective swizzle (1024 blocks % 8 == 0)
    const int bid = blockIdx.y * gridDim.x + blockIdx.x;
    const int swb = (bid & 7) * 128 + (bid >> 3);
    const int n0  = (swb & 7) * 256;    // class tile
    const int m0  = (swb >> 3) * 256;   // row tile

    const int w    = tid >> 6;
    const int lane = tid & 63;
    const int wrow = (w >> 2) * 128;    // 2M x 4N wave grid; per-wave out 128x64
    const int wcol = (w & 3) * 64;
    const int l32  = lane & 31;
    const int hi   = lane >> 5;

    // staging permutation (source-side only; LDS dest lane-linear):
    // chunk slot q holds global row=(q>>7)*32+((q>>1)&31), kchunk g=2*((q>>6)&1)+(q&1)
    const int q0 = tid;
    const int q1 = tid + 512;
    const int pr0 = (q0 >> 7) * 32 + ((q0 >> 1) & 31);
    const int pg0 = ((q0 >> 6) & 1) * 2 + (q0 & 1);
    const int pr1 = (q1 >> 7) * 32 + ((q1 >> 1) & 31);
    const int pg1 = ((q1 >> 6) & 1) * 2 + (q1 & 1);
    const size_t ga0 = (size_t)(m0 + pr0) * DIM + (size_t)(pg0 * 8);
    const size_t ga1 = (size_t)(m0 + pr1) * DIM + (size_t)(pg1 * 8);
    const size_t gb0 = (size_t)(n0 + pr0) * DIM + (size_t)(pg0 * 8);
    const size_t gb1 = (size_t)(n0 + pr1) * DIM + (size_t)(pg1 * 8);

    // reader: short idx = block*1024 + h*512 + l32*16 + hi*8 (dense 1024B per read)
    const int wb    = (w >> 2) * 4;       // A block base = wrow>>5
    const int nb    = (w & 3) * 2;        // B block base = wcol>>5
    const int rlane = l32 * 16 + hi * 8;  // offset within (block,h) slab

    f32x16 acc[4][2];
#pragma unroll
    for (int mt = 0; mt < 4; ++mt)
#pragma unroll
        for (int nt = 0; nt < 2; ++nt)
#pragma unroll
            for (int e = 0; e < 16; ++e)
                acc[mt][nt][e] = 0.f;

    // prologue: issue kt=0's staging (all 8); loop-top gate drains once
    GLDS16(Xh + ga0, &Ash[0][q0 * 8]);
    GLDS16(Xh + ga1, &Ash[0][q1 * 8]);
    GLDS16(Xl + ga0, &Asl[0][q0 * 8]);
    GLDS16(Xl + ga1, &Asl[0][q1 * 8]);
    GLDS16(Mh + gb0, &Bsh[0][q0 * 8]);
    GLDS16(Mh + gb1, &Bsh[0][q1 * 8]);
    GLDS16(Ml + gb0, &Bsl[0][q0 * 8]);
    GLDS16(Ml + gb1, &Bsl[0][q1 * 8]);

#pragma unroll 1
    for (int kt = 0; kt < 16; ++kt) {
        const int cur = kt & 1;
        const int nxt = cur ^ 1;
        const int kkn = (kt + 1) * 32;
        const bool pre = (kt < 15);

        // K-step gate: buf[cur] staged (issued a full K-step ago) + visible
        asm volatile("s_waitcnt vmcnt(0)" ::: "memory");
        __builtin_amdgcn_s_barrier();

        // B frags resident for the K-step: [nt][k-half]
        short8 bh[2][2], bl[2][2];
#pragma unroll
        for (int nt = 0; nt < 2; ++nt) {
            const int bb = (nb + nt) * 1024 + rlane;
            bh[nt][0] = *(const short8*)&Bsh[cur][bb];
            bh[nt][1] = *(const short8*)&Bsh[cur][bb + 512];
            bl[nt][0] = *(const short8*)&Bsl[cur][bb];
            bl[nt][1] = *(const short8*)&Bsl[cur][bb + 512];
        }

        // phases 0..3: A-tile p (4 reads) + stage; barrier; 12 MFMA cluster
#pragma unroll
        for (int p = 0; p < 4; ++p) {
            const int ab = (wb + p) * 1024 + rlane;
            short8 a0 = *(const short8*)&Ash[cur][ab];
            short8 a1 = *(const short8*)&Ash[cur][ab + 512];
            short8 c0 = *(const short8*)&Asl[cur][ab];
            short8 c1 = *(const short8*)&Asl[cur][ab + 512];
            if (pre) {
                if (p == 0) {
                    GLDS16(Xh + ga0 + kkn, &Ash[nxt][q0 * 8]);
                    GLDS16(Xh + ga1 + kkn, &Ash[nxt][q1 * 8]);
                } else if (p == 1) {
                    GLDS16(Xl + ga0 + kkn, &Asl[nxt][q0 * 8]);
                    GLDS16(Xl + ga1 + kkn, &Asl[nxt][q1 * 8]);
                } else if (p == 2) {
                    GLDS16(Mh + gb0 + kkn, &Bsh[nxt][q0 * 8]);
                    GLDS16(Mh + gb1 + kkn, &Bsh[nxt][q1 * 8]);
                } else {
                    GLDS16(Ml + gb0 + kkn, &Bsl[nxt][q0 * 8]);
                    GLDS16(Ml + gb1 + kkn, &Bsl[nxt][q1 * 8]);
                }
            }
            if (p == 0) asm volatile("s_waitcnt lgkmcnt(8)" ::: "memory");
            __builtin_amdgcn_sched_barrier(0);
            __builtin_amdgcn_s_barrier();
            asm volatile("s_waitcnt lgkmcnt(0)" ::: "memory");
            __builtin_amdgcn_sched_barrier(0);
            __builtin_amdgcn_s_setprio(1);
            // k-half 0: hh, hl, lh per acc
            acc[p][0] = __builtin_amdgcn_mfma_f32_32x32x16_bf16(a0, bh[0][0], acc[p][0], 0, 0, 0);
            acc[p][1] = __builtin_amdgcn_mfma_f32_32x32x16_bf16(a0, bh[1][0], acc[p][1], 0, 0, 0);
            acc[p][0] = __builtin_amdgcn_mfma_f32_32x32x16_bf16(a0, bl[0][0], acc[p][0], 0, 0, 0);
            acc[p][1] = __builtin_amdgcn_mfma_f32_32x32x16_bf16(a0, bl[1][0], acc[p][1], 0, 0, 0);
            acc[p][0] = __builtin_amdgcn_mfma_f32_32x32x16_bf16(c0, bh[0][0], acc[p][0], 0, 0, 0);
            acc[p][1] = __builtin_amdgcn_mfma_f32_32x32x16_bf16(c0, bh[1][0], acc[p][1], 0, 0, 0);
            // k-half 1: hh, hl, lh per acc
            acc[p][0] = __builtin_amdgcn_mfma_f32_32x32x16_bf16(a1, bh[0][1], acc[p][0], 0, 0, 0);
            acc[p][1] = __builtin_amdgcn_mfma_f32_32x32x16_bf16(a1, bh[1][1], acc[p][1], 0, 0, 0);
            acc[p][0] = __builtin_amdgcn_mfma_f32_32x32x16_bf16(a1, bl[0][1], acc[p][0], 0, 0, 0);
            acc[p][1] = __builtin_amdgcn_mfma_f32_32x32x16_bf16(a1, bl[1][1], acc[p][1], 0, 0, 0);
            acc[p][0] = __builtin_amdgcn_mfma_f32_32x32x16_bf16(c1, bh[0][1], acc[p][0], 0, 0, 0);
            acc[p][1] = __builtin_amdgcn_mfma_f32_32x32x16_bf16(c1, bh[1][1], acc[p][1], 0, 0, 0);
            __builtin_amdgcn_s_setprio(0);
            __builtin_amdgcn_s_barrier();
        }
    }

    // epilogue: C/D 32x32 layout col=lane&31, row=(reg&3)+8*(reg>>2)+4*hi
#pragma unroll
    for (int nt = 0; nt < 2; ++nt) {
        const int col = n0 + wcol + nt * 32 + l32;
        const float mm = m2[col];
#pragma unroll
        for (int mt = 0; mt < 4; ++mt) {
#pragma unroll
            for (int r4 = 0; r4 < 4; ++r4) {
                const int rbase = m0 + wrow + mt * 32 + r4 * 8 + hi * 4;
#pragma unroll
                for (int r = 0; r < 4; ++r)
                    S[(size_t)(rbase + r) * N_CLS + col] = 2.0f * acc[mt][nt][r4 * 4 + r] - mm;
            }
        }
    }
}

// ---------------- round-1 fallback GEMM (in-kernel split; needs no big ws) ----------------
#define LDR 40
__global__ __launch_bounds__(256) void gemm_fallback(const float* __restrict__ X,
                                                     const float* __restrict__ muK,
                                                     const float* __restrict__ m2,
                                                     float* __restrict__ S) {
    __shared__ __align__(16) short Ah[128 * LDR];
    __shared__ __align__(16) short Al[128 * LDR];
    __shared__ __align__(16) short Bh[128 * LDR];
    __shared__ __align__(16) short Bl[128 * LDR];
    const int tid  = threadIdx.x;
    const int n0   = blockIdx.x * 128;
    const int m0   = blockIdx.y * 128;
    const int w    = tid >> 6;
    const int lane = tid & 63;
    const int wm   = (w >> 1) * 64;
    const int wn   = (w & 1) * 64;
    const int l16  = lane & 15;
    const int quad = lane >> 4;
    f32x4 acc[4][4];
#pragma unroll
    for (int mt = 0; mt < 4; ++mt)
#pragma unroll
        for (int nt = 0; nt < 4; ++nt)
            acc[mt][nt] = (f32x4){0.f, 0.f, 0.f, 0.f};
    for (int kt = 0; kt < DIM; kt += 32) {
        __syncthreads();
#pragma unroll
        for (int i = 0; i < 4; ++i) {
            int idx = tid + 256 * i;
            int row = idx >> 3;
            int c4  = (idx & 7) * 4;
            float4 fa = *(const float4*)(X + (size_t)(m0 + row) * DIM + kt + c4);
            float4 fb = *(const float4*)(muK + (size_t)(n0 + row) * DIM + kt + c4);
            short h0, h1, h2, h3, l0, l1, l2, l3;
            split_bf(fa.x, h0, l0); split_bf(fa.y, h1, l1);
            split_bf(fa.z, h2, l2); split_bf(fa.w, h3, l3);
            *(short4v*)&Ah[row * LDR + c4] = (short4v){h0, h1, h2, h3};
            *(short4v*)&Al[row * LDR + c4] = (short4v){l0, l1, l2, l3};
            split_bf(fb.x, h0, l0); split_bf(fb.y, h1, l1);
            split_bf(fb.z, h2, l2); split_bf(fb.w, h3, l3);
            *(short4v*)&Bh[row * LDR + c4] = (short4v){h0, h1, h2, h3};
            *(short4v*)&Bl[row * LDR + c4] = (short4v){l0, l1, l2, l3};
        }
        __syncthreads();
        short8 ah[4], al[4];
#pragma unroll
        for (int mt = 0; mt < 4; ++mt) {
            int r = wm + mt * 16 + l16;
            ah[mt] = *(const short8*)&Ah[r * LDR + quad * 8];
            al[mt] = *(const short8*)&Al[r * LDR + quad * 8];
        }
#pragma unroll
        for (int nt = 0; nt < 4; ++nt) {
            int r = wn + nt * 16 + l16;
            short8 bh = *(const short8*)&Bh[r * LDR + quad * 8];
            short8 bl = *(const short8*)&Bl[r * LDR + quad * 8];
#pragma unroll
            for (int mt = 0; mt < 4; ++mt)
                acc[mt][nt] = __builtin_amdgcn_mfma_f32_16x16x32_bf16(ah[mt], bh, acc[mt][nt], 0, 0, 0);
#pragma unroll
            for (int mt = 0; mt < 4; ++mt)
                acc[mt][nt] = __builtin_amdgcn_mfma_f32_16x16x32_bf16(ah[mt], bl, acc[mt][nt], 0, 0, 0);
#pragma unroll
            for (int mt = 0; mt < 4; ++mt)
                acc[mt][nt] = __builtin_amdgcn_mfma_f32_16x16x32_bf16(al[mt], bh, acc[mt][nt], 0, 0, 0);
        }
    }
#pragma unroll
    for (int nt = 0; nt < 4; ++nt) {
        int col = n0 + wn + nt * 16 + l16;
        float mm = m2[col];
#pragma unroll
        for (int mt = 0; mt < 4; ++mt) {
            int rbase = m0 + wm + mt * 16 + quad * 4;
#pragma unroll
            for (int r = 0; r < 4; ++r)
                S[(size_t)(rbase + r) * N_CLS + col] = 2.0f * acc[mt][nt][r] - mm;
        }
    }
}

// ---------------- masked row softmax: wave = 4 consecutive rows, 2-row pipeline ----------
// (R5 version, best measured; unchanged)
__device__ __forceinline__ void sm_load_row(float* S, int row, int lane, f32x4* v) {
    const f32x4* pi = (const f32x4*)(S + (size_t)row * N_CLS);
#pragma unroll
    for (int i = 0; i < 8; ++i) v[i] = pi[i * 64 + lane];
}

__device__ __forceinline__ void sm_compute_store(float* S, int row, int lane,
                                                 unsigned msk, f32x4* v) {
    float mn = FLT_MAX, mx = -FLT_MAX;
#pragma unroll
    for (int i = 0; i < 8; ++i) {
        f32x4 s = v[i];
        mn = fminf(mn, fminf(fminf(s.x, s.y), fminf(s.z, s.w)));
        if (!((msk >> (i * 4 + 0)) & 1u)) mx = fmaxf(mx, s.x);
        if (!((msk >> (i * 4 + 1)) & 1u)) mx = fmaxf(mx, s.y);
        if (!((msk >> (i * 4 + 2)) & 1u)) mx = fmaxf(mx, s.z);
        if (!((msk >> (i * 4 + 3)) & 1u)) mx = fmaxf(mx, s.w);
    }
    for (int off = 32; off; off >>= 1) {
        mn = fminf(mn, __shfl_xor(mn, off));
        mx = fmaxf(mx, __shfl_xor(mx, off));
    }
    if (mx == -FLT_MAX) mx = mn - 1.0f;
    const float fill = mn - 1.0f;

    float sum = 0.f;
#pragma unroll
    for (int i = 0; i < 8; ++i) {
        f32x4 s = v[i];
        s.x = __expf(((msk >> (i * 4 + 0)) & 1u ? fill : s.x) - mx);
        s.y = __expf(((msk >> (i * 4 + 1)) & 1u ? fill : s.y) - mx);
        s.z = __expf(((msk >> (i * 4 + 2)) & 1u ? fill : s.z) - mx);
        s.w = __expf(((msk >> (i * 4 + 3)) & 1u ? fill : s.w) - mx);
        sum += s.x + s.y + s.z + s.w;
        v[i] = s;
    }
    for (int off = 32; off; off >>= 1) sum += __shfl_xor(sum, off);
    const float inv = 1.0f / sum;
    f32x4* po = (f32x4*)(S + (size_t)row * N_CLS);
#pragma unroll
    for (int i = 0; i < 8; ++i) {
        f32x4 s = v[i] * inv;
        __builtin_nontemporal_store(s, &po[i * 64 + lane]);
    }
}

__global__ __launch_bounds__(256) void softmax_kernel(float* __restrict__ S,
                                                      const float* __restrict__ cK) {
    const int w    = threadIdx.x >> 6;
    const int lane = threadIdx.x & 63;
    const float4* ck4 = (const float4*)cK;

    unsigned msk = 0;                         // row-invariant per-lane column mask
#pragma unroll
    for (int i = 0; i < 8; ++i) {
        float4 k = ck4[i * 64 + lane];
        if (k.x == 0.f) msk |= 1u << (i * 4 + 0);
        if (k.y == 0.f) msk |= 1u << (i * 4 + 1);
        if (k.z == 0.f) msk |= 1u << (i * 4 + 2);
        if (k.w == 0.f) msk |= 1u << (i * 4 + 3);
    }

    const int r0 = blockIdx.x * 16 + w * 4;   // 4 consecutive rows per wave
    f32x4 va[8], vb[8];

    sm_load_row(S, r0 + 0, lane, va);         // prologue
    sm_load_row(S, r0 + 1, lane, vb);         // row 1 in flight during row 0 compute
    sm_compute_store(S, r0 + 0, lane, msk, va);
    sm_load_row(S, r0 + 2, lane, va);
    sm_compute_store(S, r0 + 1, lane, msk, vb);
    sm_load_row(S, r0 + 3, lane, vb);
    sm_compute_store(S, r0 + 2, lane, msk, va);
    sm_compute_store(S, r0 + 3, lane, msk, vb);
}

extern "C" void kernel_launch(void* const* d_in, const int* in_sizes, int n_in,
                              void* d_out, int out_size, void* d_ws, size_t ws_size,
                              hipStream_t stream) {
    const float* X   = (const float*)d_in[0];   // (32768, 512)
    const float* muK = (const float*)d_in[1];   // (2048, 512)
    const float* cK  = (const float*)d_in[2];   // (2048,)
    float* out = (float*)d_out;                 // (32768, 2048)

    const size_t XN = (size_t)N_ROWS * DIM;     // 16.8M elems
    const size_t MN = (size_t)N_CLS * DIM;      // 1.05M elems
    const size_t need = (2 * XN + 2 * MN) * sizeof(short) + N_CLS * sizeof(float);

    if (ws_size >= need) {
        // ws layout: Xh 32MB | Xl 32MB | Mh 2MB | Ml 2MB | m2 8KB
        short* Xh = (short*)d_ws;
        short* Xl = Xh + XN;
        short* Mh = Xl + XN;
        short* Ml = Mh + MN;
        float* m2 = (float*)(Ml + MN);
        prep_kernel<<<PREP_XB + PREP_MB + PREP_M2B, 256, 0, stream>>>(X, muK, Xh, Xl, Mh, Ml, m2);
        dim3 grid256(N_CLS / 256, N_ROWS / 256);   // 8 x 128 = 1024 blocks
        gemm_kernel<<<grid256, 512, 0, stream>>>(Xh, Xl, Mh, Ml, m2, out);
    } else {
        float* m2f = (float*)d_ws;
        m2_kernel<<<N_CLS, 256, 0, stream>>>(muK, m2f);
        dim3 grid128(N_CLS / 128, N_ROWS / 128);
        gemm_fallback<<<grid128, 256, 0, stream>>>(X, muK, m2f, out);
    }
    softmax_kernel<<<N_ROWS / 16, 256, 0, stream>>>(out, cK);
}

// Round 13
// 547.282 us; speedup vs baseline: 1.0099x; 1.0099x over previous
//
#include <hip/hip_runtime.h>
#include <cfloat>

// Problem constants
#define N_ROWS 32768
#define N_CLS  2048
#define DIM    512

typedef __attribute__((ext_vector_type(8))) short short8;
typedef __attribute__((ext_vector_type(4))) short short4v;
typedef __attribute__((ext_vector_type(4))) float f32x4;

__device__ __forceinline__ unsigned f2bf_bits(float x) {
    union { float f; unsigned u; } a; a.f = x;
    return (a.u + 0x7fffu + ((a.u >> 16) & 1u)) >> 16;   // RNE
}
__device__ __forceinline__ float bf_to_f(unsigned bits) {
    union { unsigned u; float f; } a; a.u = bits << 16;
    return a.f;
}
__device__ __forceinline__ void split_bf(float x, short &h, short &l) {
    unsigned hb = f2bf_bits(x);
    h = (short)hb;
    float r = x - bf_to_f(hb);          // exact residual
    l = (short)f2bf_bits(r);
}

// ---------------- fused prep: split X, split muK, m2 — one launch ----------------
// Block-range dispatch replaces 3 kernels (saves 2 launch gaps). All work
// independent; branch is block-uniform. Math identical to the old kernels.
#define PREP_XB   16384
#define PREP_MB   1024
#define PREP_M2B  2048
__global__ __launch_bounds__(256) void prep_kernel(const float* __restrict__ X,
                                                   const float* __restrict__ muK,
                                                   short* __restrict__ Xh,
                                                   short* __restrict__ Xl,
                                                   short* __restrict__ Mh,
                                                   short* __restrict__ Ml,
                                                   float* __restrict__ m2) {
    const int b = blockIdx.x;
    if (b < PREP_XB + PREP_MB) {
        const bool isX = (b < PREP_XB);
        const float* src = isX ? X : muK;
        short* hi = isX ? Xh : Mh;
        short* lo = isX ? Xl : Ml;
        const int idx = (isX ? b : b - PREP_XB) * 256 + threadIdx.x;
        float4 v = ((const float4*)src)[idx];
        short h0, h1, h2, h3, l0, l1, l2, l3;
        split_bf(v.x, h0, l0); split_bf(v.y, h1, l1);
        split_bf(v.z, h2, l2); split_bf(v.w, h3, l3);
        ((short4v*)hi)[idx] = (short4v){h0, h1, h2, h3};
        ((short4v*)lo)[idx] = (short4v){l0, l1, l2, l3};
    } else {
        const int j = b - (PREP_XB + PREP_MB);
        const int t = threadIdx.x;
        const float* r = muK + (size_t)j * DIM;
        float a = r[t], c = r[t + 256];
        float s = a * a + c * c;
        for (int off = 32; off; off >>= 1) s += __shfl_xor(s, off);
        __shared__ float sw[4];
        if ((t & 63) == 0) sw[t >> 6] = s;
        __syncthreads();
        if (t == 0) m2[j] = sw[0] + sw[1] + sw[2] + sw[3];
    }
}

// ---------------- m2 standalone (fallback path only) ----------------
__global__ __launch_bounds__(256) void m2_kernel(const float* __restrict__ muK,
                                                 float* __restrict__ m2) {
    const int j = blockIdx.x;
    const int t = threadIdx.x;
    const float* r = muK + (size_t)j * DIM;
    float a = r[t], b = r[t + 256];
    float s = a * a + b * b;
    for (int off = 32; off; off >>= 1) s += __shfl_xor(s, off);
    __shared__ float sw[4];
    if ((t & 63) == 0) sw[t >> 6] = s;
    __syncthreads();
    if (t == 0) m2[j] = sw[0] + sw[1] + sw[2] + sw[3];
}

#define GLDS16(g, l) __builtin_amdgcn_global_load_lds( \
    (const __attribute__((address_space(1))) unsigned int*)(g), \
    (__attribute__((address_space(3))) unsigned int*)(l), 16, 0, 0)

// ---------------- fused bf16x3 GEMM: 256x256 tile, 8 waves, m201 8-phase (R5/R9 best) ----
// S[i,j] = 2 * (Xh.Mh + Xh.Ml + Xl.Mh)[i,j] - m2[j]
// R13: exact revert to R9 (best verified: gemm 204 us, 0 bank conflicts).
// 32x32x16 branch (R10-R12) closed: +21% pipe rate was fully consumed by an
// LDS-side cost (12.58M conflicts) that did not respond to read-layout changes
// (R12: total reorganization, counter unchanged, duration worse) -> conflict
// source not read-side; model falsified twice; branch measured-worse overall.
// 12 gemm configs across R0-R12 bracket this structure at 204-255 us with
// MfmaUtil pinned 34-45% -> empirical plateau for this decomposition.
__global__ __launch_bounds__(512, 2) void gemm_kernel(const short* __restrict__ Xh,
                                                      const short* __restrict__ Xl,
                                                      const short* __restrict__ Mh,
                                                      const short* __restrict__ Ml,
                                                      const float* __restrict__ m2,
                                                      float* __restrict__ S) {
    __shared__ __align__(16) short Ash[2][256 * 32];
    __shared__ __align__(16) short Asl[2][256 * 32];
    __shared__ __align__(16) short Bsh[2][256 * 32];
    __shared__ __align__(16) short Bsl[2][256 * 32];

    const int tid = threadIdx.x;

    // XCD-chunked bijective swizzle (1024 blocks % 8 == 0)
    const int bid = blockIdx.y * gridDim.x + blockIdx.x;
    const int swb = (bid & 7) * 128 + (bid >> 3);
    const int n0  = (swb & 7) * 256;    // class tile
    const int m0  = (swb >> 3) * 256;   // row tile

    const int w    = tid >> 6;
    const int lane = tid & 63;
    const int wrow = (w >> 2) * 128;    // 2M x 4N wave grid; per-wave out 128x64
    const int wcol = (w & 3) * 64;
    const int l16  = lane & 15;
    const int quad = lane >> 4;

    const int q0 = tid;
    const int q1 = tid + 512;
    const size_t ga0 = (size_t)(m0 + (q0 >> 2)) * DIM + (size_t)(((q0 & 3) ^ ((q0 >> 3) & 3)) * 8);
    const size_t ga1 = (size_t)(m0 + (q1 >> 2)) * DIM + (size_t)(((q1 & 3) ^ ((q1 >> 3) & 3)) * 8);
    const size_t gb0 = (size_t)(n0 + (q0 >> 2)) * DIM + (size_t)(((q0 & 3) ^ ((q0 >> 3) & 3)) * 8);
    const size_t gb1 = (size_t)(n0 + (q1 >> 2)) * DIM + (size_t)(((q1 & 3) ^ ((q1 >> 3) & 3)) * 8);

    // reader swizzle: row bits [2:1] equal l16 bits [2:1]
    const int sw = (quad ^ ((l16 >> 1) & 3)) * 8;

    f32x4 acc[8][4];
#pragma unroll
    for (int mt = 0; mt < 8; ++mt)
#pragma unroll
        for (int nt = 0; nt < 4; ++nt)
            acc[mt][nt] = (f32x4){0.f, 0.f, 0.f, 0.f};

    // prologue: issue kt=0's staging (all 8); loop-top gate drains once
    GLDS16(Xh + ga0, &Ash[0][q0 * 8]);
    GLDS16(Xh + ga1, &Ash[0][q1 * 8]);
    GLDS16(Xl + ga0, &Asl[0][q0 * 8]);
    GLDS16(Xl + ga1, &Asl[0][q1 * 8]);
    GLDS16(Mh + gb0, &Bsh[0][q0 * 8]);
    GLDS16(Mh + gb1, &Bsh[0][q1 * 8]);
    GLDS16(Ml + gb0, &Bsl[0][q0 * 8]);
    GLDS16(Ml + gb1, &Bsl[0][q1 * 8]);

#pragma unroll 1
    for (int kt = 0; kt < 16; ++kt) {
        const int cur = kt & 1;
        const int nxt = cur ^ 1;
        const int kkn = (kt + 1) * 32;
        const bool pre = (kt < 15);

        // K-step gate: buf[cur] staged (issued a full K-step ago) + visible
        asm volatile("s_waitcnt vmcnt(0)" ::: "memory");
        __builtin_amdgcn_s_barrier();

        short8 bh[4], bl[4];

        // ---------- phase 0: read B[0..3] + A-pair 0 (12 reads); stage Xh ----------
#pragma unroll
        for (int nt = 0; nt < 4; ++nt) {
            const int ro = (wcol + nt * 16 + l16) * 32 + sw;
            bh[nt] = *(const short8*)&Bsh[cur][ro];
            bl[nt] = *(const short8*)&Bsl[cur][ro];
        }
        {
            const int roA = (wrow + 0 * 16 + l16) * 32 + sw;
            const int roB = (wrow + 1 * 16 + l16) * 32 + sw;
            short8 ahA = *(const short8*)&Ash[cur][roA];
            short8 alA = *(const short8*)&Asl[cur][roA];
            short8 ahB = *(const short8*)&Ash[cur][roB];
            short8 alB = *(const short8*)&Asl[cur][roB];
            if (pre) {
                GLDS16(Xh + ga0 + kkn, &Ash[nxt][q0 * 8]);
                GLDS16(Xh + ga1 + kkn, &Ash[nxt][q1 * 8]);
            }
            asm volatile("s_waitcnt lgkmcnt(8)" ::: "memory");
            __builtin_amdgcn_sched_barrier(0);
            __builtin_amdgcn_s_barrier();
            asm volatile("s_waitcnt lgkmcnt(0)" ::: "memory");
            __builtin_amdgcn_sched_barrier(0);
            __builtin_amdgcn_s_setprio(1);
#pragma unroll
            for (int nt = 0; nt < 4; ++nt) {
                acc[0][nt] = __builtin_amdgcn_mfma_f32_16x16x32_bf16(ahA, bh[nt], acc[0][nt], 0, 0, 0);
                acc[1][nt] = __builtin_amdgcn_mfma_f32_16x16x32_bf16(ahB, bh[nt], acc[1][nt], 0, 0, 0);
                acc[0][nt] = __builtin_amdgcn_mfma_f32_16x16x32_bf16(ahA, bl[nt], acc[0][nt], 0, 0, 0);
                acc[1][nt] = __builtin_amdgcn_mfma_f32_16x16x32_bf16(ahB, bl[nt], acc[1][nt], 0, 0, 0);
                acc[0][nt] = __builtin_amdgcn_mfma_f32_16x16x32_bf16(alA, bh[nt], acc[0][nt], 0, 0, 0);
                acc[1][nt] = __builtin_amdgcn_mfma_f32_16x16x32_bf16(alB, bh[nt], acc[1][nt], 0, 0, 0);
            }
            __builtin_amdgcn_s_setprio(0);
            __builtin_amdgcn_s_barrier();
        }

        // ---------- phases 1..3: A-pair p (4 reads); stage Xl/Mh/Ml ----------
#pragma unroll
        for (int p = 1; p < 4; ++p) {
            const int mtA = 2 * p, mtB = 2 * p + 1;
            const int roA = (wrow + mtA * 16 + l16) * 32 + sw;
            const int roB = (wrow + mtB * 16 + l16) * 32 + sw;
            short8 ahA = *(const short8*)&Ash[cur][roA];
            short8 alA = *(const short8*)&Asl[cur][roA];
            short8 ahB = *(const short8*)&Ash[cur][roB];
            short8 alB = *(const short8*)&Asl[cur][roB];
            if (pre) {
                if (p == 1) {
                    GLDS16(Xl + ga0 + kkn, &Asl[nxt][q0 * 8]);
                    GLDS16(Xl + ga1 + kkn, &Asl[nxt][q1 * 8]);
                } else if (p == 2) {
                    GLDS16(Mh + gb0 + kkn, &Bsh[nxt][q0 * 8]);
                    GLDS16(Mh + gb1 + kkn, &Bsh[nxt][q1 * 8]);
                } else {
                    GLDS16(Ml + gb0 + kkn, &Bsl[nxt][q0 * 8]);
                    GLDS16(Ml + gb1 + kkn, &Bsl[nxt][q1 * 8]);
                }
            }
            __builtin_amdgcn_sched_barrier(0);
            __builtin_amdgcn_s_barrier();
            asm volatile("s_waitcnt lgkmcnt(0)" ::: "memory");
            __builtin_amdgcn_sched_barrier(0);
            __builtin_amdgcn_s_setprio(1);
#pragma unroll
            for (int nt = 0; nt < 4; ++nt) {
                acc[mtA][nt] = __builtin_amdgcn_mfma_f32_16x16x32_bf16(ahA, bh[nt], acc[mtA][nt], 0, 0, 0);
                acc[mtB][nt] = __builtin_amdgcn_mfma_f32_16x16x32_bf16(ahB, bh[nt], acc[mtB][nt], 0, 0, 0);
                acc[mtA][nt] = __builtin_amdgcn_mfma_f32_16x16x32_bf16(ahA, bl[nt], acc[mtA][nt], 0, 0, 0);
                acc[mtB][nt] = __builtin_amdgcn_mfma_f32_16x16x32_bf16(ahB, bl[nt], acc[mtB][nt], 0, 0, 0);
                acc[mtA][nt] = __builtin_amdgcn_mfma_f32_16x16x32_bf16(alA, bh[nt], acc[mtA][nt], 0, 0, 0);
                acc[mtB][nt] = __builtin_amdgcn_mfma_f32_16x16x32_bf16(alB, bh[nt], acc[mtB][nt], 0, 0, 0);
            }
            __builtin_amdgcn_s_setprio(0);
            __builtin_amdgcn_s_barrier();
        }
    }

    // epilogue: C/D layout col=lane&15, row=quad*4+reg
#pragma unroll
    for (int nt = 0; nt < 4; ++nt) {
        int col = n0 + wcol + nt * 16 + l16;
        float mm = m2[col];
#pragma unroll
        for (int mt = 0; mt < 8; ++mt) {
            int rbase = m0 + wrow + mt * 16 + quad * 4;
#pragma unroll
            for (int r = 0; r < 4; ++r)
                S[(size_t)(rbase + r) * N_CLS + col] = 2.0f * acc[mt][nt][r] - mm;
        }
    }
}

// ---------------- round-1 fallback GEMM (in-kernel split; needs no big ws) ----------------
#define LDR 40
__global__ __launch_bounds__(256) void gemm_fallback(const float* __restrict__ X,
                                                     const float* __restrict__ muK,
                                                     const float* __restrict__ m2,
                                                     float* __restrict__ S) {
    __shared__ __align__(16) short Ah[128 * LDR];
    __shared__ __align__(16) short Al[128 * LDR];
    __shared__ __align__(16) short Bh[128 * LDR];
    __shared__ __align__(16) short Bl[128 * LDR];
    const int tid  = threadIdx.x;
    const int n0   = blockIdx.x * 128;
    const int m0   = blockIdx.y * 128;
    const int w    = tid >> 6;
    const int lane = tid & 63;
    const int wm   = (w >> 1) * 64;
    const int wn   = (w & 1) * 64;
    const int l16  = lane & 15;
    const int quad = lane >> 4;
    f32x4 acc[4][4];
#pragma unroll
    for (int mt = 0; mt < 4; ++mt)
#pragma unroll
        for (int nt = 0; nt < 4; ++nt)
            acc[mt][nt] = (f32x4){0.f, 0.f, 0.f, 0.f};
    for (int kt = 0; kt < DIM; kt += 32) {
        __syncthreads();
#pragma unroll
        for (int i = 0; i < 4; ++i) {
            int idx = tid + 256 * i;
            int row = idx >> 3;
            int c4  = (idx & 7) * 4;
            float4 fa = *(const float4*)(X + (size_t)(m0 + row) * DIM + kt + c4);
            float4 fb = *(const float4*)(muK + (size_t)(n0 + row) * DIM + kt + c4);
            short h0, h1, h2, h3, l0, l1, l2, l3;
            split_bf(fa.x, h0, l0); split_bf(fa.y, h1, l1);
            split_bf(fa.z, h2, l2); split_bf(fa.w, h3, l3);
            *(short4v*)&Ah[row * LDR + c4] = (short4v){h0, h1, h2, h3};
            *(short4v*)&Al[row * LDR + c4] = (short4v){l0, l1, l2, l3};
            split_bf(fb.x, h0, l0); split_bf(fb.y, h1, l1);
            split_bf(fb.z, h2, l2); split_bf(fb.w, h3, l3);
            *(short4v*)&Bh[row * LDR + c4] = (short4v){h0, h1, h2, h3};
            *(short4v*)&Bl[row * LDR + c4] = (short4v){l0, l1, l2, l3};
        }
        __syncthreads();
        short8 ah[4], al[4];
#pragma unroll
        for (int mt = 0; mt < 4; ++mt) {
            int r = wm + mt * 16 + l16;
            ah[mt] = *(const short8*)&Ah[r * LDR + quad * 8];
            al[mt] = *(const short8*)&Al[r * LDR + quad * 8];
        }
#pragma unroll
        for (int nt = 0; nt < 4; ++nt) {
            int r = wn + nt * 16 + l16;
            short8 bh = *(const short8*)&Bh[r * LDR + quad * 8];
            short8 bl = *(const short8*)&Bl[r * LDR + quad * 8];
#pragma unroll
            for (int mt = 0; mt < 4; ++mt)
                acc[mt][nt] = __builtin_amdgcn_mfma_f32_16x16x32_bf16(ah[mt], bh, acc[mt][nt], 0, 0, 0);
#pragma unroll
            for (int mt = 0; mt < 4; ++mt)
                acc[mt][nt] = __builtin_amdgcn_mfma_f32_16x16x32_bf16(ah[mt], bl, acc[mt][nt], 0, 0, 0);
#pragma unroll
            for (int mt = 0; mt < 4; ++mt)
                acc[mt][nt] = __builtin_amdgcn_mfma_f32_16x16x32_bf16(al[mt], bh, acc[mt][nt], 0, 0, 0);
        }
    }
#pragma unroll
    for (int nt = 0; nt < 4; ++nt) {
        int col = n0 + wn + nt * 16 + l16;
        float mm = m2[col];
#pragma unroll
        for (int mt = 0; mt < 4; ++mt) {
            int rbase = m0 + wm + mt * 16 + quad * 4;
#pragma unroll
            for (int r = 0; r < 4; ++r)
                S[(size_t)(rbase + r) * N_CLS + col] = 2.0f * acc[mt][nt][r] - mm;
        }
    }
}

// ---------------- masked row softmax: wave = 4 consecutive rows, 2-row pipeline ----------
// (R5 version — best measured; R8 A/B confirmed 4-row ILP + NT stores)
__device__ __forceinline__ void sm_load_row(float* S, int row, int lane, f32x4* v) {
    const f32x4* pi = (const f32x4*)(S + (size_t)row * N_CLS);
#pragma unroll
    for (int i = 0; i < 8; ++i) v[i] = pi[i * 64 + lane];
}

__device__ __forceinline__ void sm_compute_store(float* S, int row, int lane,
                                                 unsigned msk, f32x4* v) {
    float mn = FLT_MAX, mx = -FLT_MAX;
#pragma unroll
    for (int i = 0; i < 8; ++i) {
        f32x4 s = v[i];
        mn = fminf(mn, fminf(fminf(s.x, s.y), fminf(s.z, s.w)));
        if (!((msk >> (i * 4 + 0)) & 1u)) mx = fmaxf(mx, s.x);
        if (!((msk >> (i * 4 + 1)) & 1u)) mx = fmaxf(mx, s.y);
        if (!((msk >> (i * 4 + 2)) & 1u)) mx = fmaxf(mx, s.z);
        if (!((msk >> (i * 4 + 3)) & 1u)) mx = fmaxf(mx, s.w);
    }
    for (int off = 32; off; off >>= 1) {
        mn = fminf(mn, __shfl_xor(mn, off));
        mx = fmaxf(mx, __shfl_xor(mx, off));
    }
    if (mx == -FLT_MAX) mx = mn - 1.0f;
    const float fill = mn - 1.0f;

    float sum = 0.f;
#pragma unroll
    for (int i = 0; i < 8; ++i) {
        f32x4 s = v[i];
        s.x = __expf(((msk >> (i * 4 + 0)) & 1u ? fill : s.x) - mx);
        s.y = __expf(((msk >> (i * 4 + 1)) & 1u ? fill : s.y) - mx);
        s.z = __expf(((msk >> (i * 4 + 2)) & 1u ? fill : s.z) - mx);
        s.w = __expf(((msk >> (i * 4 + 3)) & 1u ? fill : s.w) - mx);
        sum += s.x + s.y + s.z + s.w;
        v[i] = s;
    }
    for (int off = 32; off; off >>= 1) sum += __shfl_xor(sum, off);
    const float inv = 1.0f / sum;
    f32x4* po = (f32x4*)(S + (size_t)row * N_CLS);
#pragma unroll
    for (int i = 0; i < 8; ++i) {
        f32x4 s = v[i] * inv;
        __builtin_nontemporal_store(s, &po[i * 64 + lane]);
    }
}

__global__ __launch_bounds__(256) void softmax_kernel(float* __restrict__ S,
                                                      const float* __restrict__ cK) {
    const int w    = threadIdx.x >> 6;
    const int lane = threadIdx.x & 63;
    const float4* ck4 = (const float4*)cK;

    unsigned msk = 0;                         // row-invariant per-lane column mask
#pragma unroll
    for (int i = 0; i < 8; ++i) {
        float4 k = ck4[i * 64 + lane];
        if (k.x == 0.f) msk |= 1u << (i * 4 + 0);
        if (k.y == 0.f) msk |= 1u << (i * 4 + 1);
        if (k.z == 0.f) msk |= 1u << (i * 4 + 2);
        if (k.w == 0.f) msk |= 1u << (i * 4 + 3);
    }

    const int r0 = blockIdx.x * 16 + w * 4;   // 4 consecutive rows per wave
    f32x4 va[8], vb[8];

    sm_load_row(S, r0 + 0, lane, va);         // prologue
    sm_load_row(S, r0 + 1, lane, vb);         // row 1 in flight during row 0 compute
    sm_compute_store(S, r0 + 0, lane, msk, va);
    sm_load_row(S, r0 + 2, lane, va);
    sm_compute_store(S, r0 + 1, lane, msk, vb);
    sm_load_row(S, r0 + 3, lane, vb);
    sm_compute_store(S, r0 + 2, lane, msk, va);
    sm_compute_store(S, r0 + 3, lane, msk, vb);
}

extern "C" void kernel_launch(void* const* d_in, const int* in_sizes, int n_in,
                              void* d_out, int out_size, void* d_ws, size_t ws_size,
                              hipStream_t stream) {
    const float* X   = (const float*)d_in[0];   // (32768, 512)
    const float* muK = (const float*)d_in[1];   // (2048, 512)
    const float* cK  = (const float*)d_in[2];   // (2048,)
    float* out = (float*)d_out;                 // (32768, 2048)

    const size_t XN = (size_t)N_ROWS * DIM;     // 16.8M elems
    const size_t MN = (size_t)N_CLS * DIM;      // 1.05M elems
    const size_t need = (2 * XN + 2 * MN) * sizeof(short) + N_CLS * sizeof(float);

    if (ws_size >= need) {
        // ws layout: Xh 32MB | Xl 32MB | Mh 2MB | Ml 2MB | m2 8KB
        short* Xh = (short*)d_ws;
        short* Xl = Xh + XN;
        short* Mh = Xl + XN;
        short* Ml = Mh + MN;
        float* m2 = (float*)(Ml + MN);
        prep_kernel<<<PREP_XB + PREP_MB + PREP_M2B, 256, 0, stream>>>(X, muK, Xh, Xl, Mh, Ml, m2);
        dim3 grid256(N_CLS / 256, N_ROWS / 256);   // 8 x 128 = 1024 blocks
        gemm_kernel<<<grid256, 512, 0, stream>>>(Xh, Xl, Mh, Ml, m2, out);
    } else {
        float* m2f = (float*)d_ws;
        m2_kernel<<<N_CLS, 256, 0, stream>>>(muK, m2f);
        dim3 grid128(N_CLS / 128, N_ROWS / 128);
        gemm_fallback<<<grid128, 256, 0, stream>>>(X, muK, m2f, out);
    }
    softmax_kernel<<<N_ROWS / 16, 256, 0, stream>>>(out, cK);
}